// Round 2
// baseline (643.492 us; speedup 1.0000x reference)
//
#include <hip/hip_runtime.h>

typedef unsigned short u16;
typedef unsigned int u32;
typedef float f32x4 __attribute__((ext_vector_type(4)));
typedef __bf16 bf16x8 __attribute__((ext_vector_type(8)));

__device__ __forceinline__ u16 f2bf(float f) {
  unsigned u = __builtin_bit_cast(unsigned, f);
  u += 0x7FFFu + ((u >> 16) & 1u);
  return (u16)(u >> 16);
}
__device__ __forceinline__ u32 pack2(float a, float b) {
  return (u32)f2bf(a) | ((u32)f2bf(b) << 16);
}

// ---- prep: convert weights f32->bf16 into ws, expand rel-pos bias to [8][64][64] f32
__global__ void prep_kern(const float* __restrict__ qw_f, const float* __restrict__ kvw_f,
                          const float* __restrict__ pjw_f, const float* __restrict__ rpb,
                          u16* __restrict__ qw, u16* __restrict__ kvw, u16* __restrict__ pjw,
                          float* __restrict__ biasf) {
  int i = blockIdx.x * 256 + threadIdx.x;
  if (i < 65536) {
    qw[i] = f2bf(qw_f[i]);
  } else if (i < 196608) {
    kvw[i - 65536] = f2bf(kvw_f[i - 65536]);
  } else if (i < 262144) {
    pjw[i - 196608] = f2bf(pjw_f[i - 196608]);
  } else if (i < 294912) {
    int t = i - 262144;                 // [h][n][m]
    int h = t >> 12, n = (t >> 6) & 63, m = t & 63;
    int r1 = n >> 3, c1 = n & 7, r2 = m >> 3, c2 = m & 7;
    int rp = (r1 - r2 + 7) * 15 + (c1 - c2 + 7);
    biasf[t] = rpb[rp * 8 + h];
  }
}

// LDS: two 33792B regions. R0: stage (ref->adj) then VT-swizzled [256][64].
//      R1: Q tile [64][264] then O tile [64][264].
#define XROW 528
#define R0_OFF 0
#define R1_OFF 33792
#define LDS_TOTAL 67584

__global__ __launch_bounds__(512, 4) void winattn_kern(
    const float* __restrict__ xr_g, const float* __restrict__ xa_g,
    const float* __restrict__ mask_g,
    const float* __restrict__ qb_g, const float* __restrict__ kvb_g, const float* __restrict__ pb_g,
    const u16* __restrict__ qw, const u16* __restrict__ kvw, const u16* __restrict__ pjw,
    const float* __restrict__ biasf, float* __restrict__ out_g, int nW) {
  extern __shared__ char smem[];
  const int tid = threadIdx.x;
  const int l = tid & 63, wv = tid >> 6;
  const int lr = l & 15, lq = l >> 4;
  const int b = blockIdx.x;
  const int wd = b % nW;
  const float scale = 0.17677669529663687f;  // 1/sqrt(32)

  // ---- prefetch ref + adj [64][256] f32 tiles into registers
  const float* refb = xr_g + (size_t)b * 16384;
  const float* adjb = xa_g + (size_t)b * 16384;
  float4 rv[8], av[8];
#pragma unroll
  for (int it = 0; it < 8; ++it) {
    int flat = it * 512 + tid;
    rv[it] = *(const float4*)(refb + (flat >> 6) * 256 + ((flat & 63) << 2));
  }
#pragma unroll
  for (int it = 0; it < 8; ++it) {
    int flat = it * 512 + tid;
    av[it] = *(const float4*)(adjb + (flat >> 6) * 256 + ((flat & 63) << 2));
  }

  auto stw = [&](int it, u32 lo, u32 hi) {
    int flat = it * 512 + tid;
    int t = flat >> 6, c4 = (flat & 63) << 2;
    uint2 w;
    w.x = lo;
    w.y = hi;
    *(uint2*)(smem + R0_OFF + t * XROW + c4 * 2) = w;
  };

#pragma unroll
  for (int it = 0; it < 8; ++it) stw(it, pack2(rv[it].x, rv[it].y), pack2(rv[it].z, rv[it].w));
  __syncthreads();  // B1: ref staged

  // ---- Q-gemm (transposed): D[c][t] = sum_k qw[c][k]*x[t][k]; store [t][c] into R1
  {
    f32x4 acc[2][4];
#pragma unroll
    for (int i = 0; i < 2; ++i)
#pragma unroll
      for (int j = 0; j < 4; ++j) acc[i][j] = {0.f, 0.f, 0.f, 0.f};
    const int row0 = wv * 32 + lr;
    const int kl = 8 * lq;
#pragma unroll
    for (int kk = 0; kk < 8; ++kk) {
      int c = kk * 32 + kl;
      bf16x8 a0 = *(const bf16x8*)(qw + (row0) * 256 + c);
      bf16x8 a1 = *(const bf16x8*)(qw + (row0 + 16) * 256 + c);
#pragma unroll
      for (int nt = 0; nt < 4; ++nt) {
        bf16x8 bt = *(const bf16x8*)(smem + R0_OFF + (nt * 16 + lr) * XROW + c * 2);
        acc[0][nt] = __builtin_amdgcn_mfma_f32_16x16x32_bf16(a0, bt, acc[0][nt], 0, 0, 0);
        acc[1][nt] = __builtin_amdgcn_mfma_f32_16x16x32_bf16(a1, bt, acc[1][nt], 0, 0, 0);
      }
    }
#pragma unroll
    for (int mt = 0; mt < 2; ++mt) {
      int cb = wv * 32 + mt * 16 + 4 * lq;
      float4 b4 = *(const float4*)(qb_g + cb);
#pragma unroll
      for (int nt = 0; nt < 4; ++nt) {
        int t = lr + nt * 16;
        uint2 w;
        w.x = pack2((acc[mt][nt][0] + b4.x) * scale, (acc[mt][nt][1] + b4.y) * scale);
        w.y = pack2((acc[mt][nt][2] + b4.z) * scale, (acc[mt][nt][3] + b4.w) * scale);
        *(uint2*)(smem + R1_OFF + t * XROW + cb * 2) = w;
      }
    }
  }
  __syncthreads();  // B2: Q-gemm reads of R0 done

#pragma unroll
  for (int it = 0; it < 8; ++it) stw(it, pack2(av[it].x, av[it].y), pack2(av[it].z, av[it].w));
  __syncthreads();  // B3: adj staged

  const int srcA = lr + 32 * (lq & 1);
  const int srcB = srcA + 16;
  const bool hi = (lq >> 1) != 0;

  // ---- K-gemm (transposed, acc in regs) then in-wave transpose -> A-fragments
  bf16x8 afr[4];
  {
    f32x4 kacc[2][4];
#pragma unroll
    for (int i = 0; i < 2; ++i)
#pragma unroll
      for (int j = 0; j < 4; ++j) kacc[i][j] = {0.f, 0.f, 0.f, 0.f};
    const int row0 = wv * 32 + lr;
    const int kl = 8 * lq;
#pragma unroll
    for (int kk = 0; kk < 8; ++kk) {
      int c = kk * 32 + kl;
      bf16x8 a0 = *(const bf16x8*)(kvw + (row0) * 256 + c);
      bf16x8 a1 = *(const bf16x8*)(kvw + (row0 + 16) * 256 + c);
#pragma unroll
      for (int nt = 0; nt < 4; ++nt) {
        bf16x8 bt = *(const bf16x8*)(smem + R0_OFF + (nt * 16 + lr) * XROW + c * 2);
        kacc[0][nt] = __builtin_amdgcn_mfma_f32_16x16x32_bf16(a0, bt, kacc[0][nt], 0, 0, 0);
        kacc[1][nt] = __builtin_amdgcn_mfma_f32_16x16x32_bf16(a1, bt, kacc[1][nt], 0, 0, 0);
      }
    }
    // bias: channel = wv*32 + mt*16 + 4lq + j
    float4 kb0 = *(const float4*)(kvb_g + wv * 32 + 4 * lq);
    float4 kb1 = *(const float4*)(kvb_g + wv * 32 + 16 + 4 * lq);
#pragma unroll
    for (int nt = 0; nt < 4; ++nt) {
      kacc[0][nt][0] += kb0.x; kacc[0][nt][1] += kb0.y; kacc[0][nt][2] += kb0.z; kacc[0][nt][3] += kb0.w;
      kacc[1][nt][0] += kb1.x; kacc[1][nt][1] += kb1.y; kacc[1][nt][2] += kb1.z; kacc[1][nt][3] += kb1.w;
    }
    // transpose: afr[nt] lane(lr,lq) = K[t=nt*16+lr][ch=8lq..8lq+7]
#pragma unroll
    for (int nt = 0; nt < 4; ++nt) {
      u32 s0 = pack2(kacc[0][nt][0], kacc[0][nt][1]);
      u32 s1 = pack2(kacc[0][nt][2], kacc[0][nt][3]);
      u32 s2 = pack2(kacc[1][nt][0], kacc[1][nt][1]);
      u32 s3 = pack2(kacc[1][nt][2], kacc[1][nt][3]);
      u32 a00 = (u32)__shfl((int)s0, srcA), a20 = (u32)__shfl((int)s2, srcA);
      u32 a01 = (u32)__shfl((int)s1, srcA), a21 = (u32)__shfl((int)s3, srcA);
      u32 b00 = (u32)__shfl((int)s0, srcB), b20 = (u32)__shfl((int)s2, srcB);
      u32 b01 = (u32)__shfl((int)s1, srcB), b21 = (u32)__shfl((int)s3, srcB);
      uint4 u;
      u.x = hi ? a20 : a00;
      u.y = hi ? a21 : a01;
      u.z = hi ? b20 : b00;
      u.w = hi ? b21 : b01;
      afr[nt] = __builtin_bit_cast(bf16x8, u);
    }
  }

  // ---- V-gemm (non-transposed, acc in regs)
  f32x4 vacc[4][2];
  {
#pragma unroll
    for (int i = 0; i < 4; ++i)
#pragma unroll
      for (int j = 0; j < 2; ++j) vacc[i][j] = {0.f, 0.f, 0.f, 0.f};
    const int kl = 8 * lq;
    const int vrow0 = 256 + wv * 32 + lr;
#pragma unroll
    for (int kk = 0; kk < 8; ++kk) {
      int c = kk * 32 + kl;
      bf16x8 b0 = *(const bf16x8*)(kvw + (vrow0) * 256 + c);
      bf16x8 b1 = *(const bf16x8*)(kvw + (vrow0 + 16) * 256 + c);
#pragma unroll
      for (int mt = 0; mt < 4; ++mt) {
        bf16x8 at = *(const bf16x8*)(smem + R0_OFF + (mt * 16 + lr) * XROW + c * 2);
        vacc[mt][0] = __builtin_amdgcn_mfma_f32_16x16x32_bf16(at, b0, vacc[mt][0], 0, 0, 0);
        vacc[mt][1] = __builtin_amdgcn_mfma_f32_16x16x32_bf16(at, b1, vacc[mt][1], 0, 0, 0);
      }
    }
    float bv0 = kvb_g[256 + wv * 32 + lr];
    float bv1 = kvb_g[256 + wv * 32 + 16 + lr];
#pragma unroll
    for (int mt = 0; mt < 4; ++mt)
#pragma unroll
      for (int j = 0; j < 4; ++j) {
        vacc[mt][0][j] += bv0;
        vacc[mt][1][j] += bv1;
      }
  }

  // ---- Q fragments from R1 (own wave's columns)
  bf16x8 bfr[4];
  {
    const int c0 = wv * 32 + 8 * lq;
#pragma unroll
    for (int nt = 0; nt < 4; ++nt)
      bfr[nt] = *(const bf16x8*)(smem + R1_OFF + (nt * 16 + lr) * XROW + c0 * 2);
  }
  __syncthreads();  // B4: all R0 reads done; VT may overwrite R0

  // ---- write VT (swizzled [256 ch][64 tok] bf16) into R0
  {
#pragma unroll
    for (int ntl = 0; ntl < 2; ++ntl) {
      int ch = wv * 32 + ntl * 16 + lr;
      int swz = (ch & 7) << 4;
      char* base = smem + R0_OFF + ch * 128;
#pragma unroll
      for (int mt = 0; mt < 4; ++mt) {
        int tB = (mt * 16 + 4 * lq) * 2;
        uint2 w;
        w.x = pack2(vacc[mt][ntl][0], vacc[mt][ntl][1]);
        w.y = pack2(vacc[mt][ntl][2], vacc[mt][ntl][3]);
        *(uint2*)(base + (tB ^ swz)) = w;
      }
    }
  }

  // ---- QK^T + softmax (head h = wv)
  f32x4 sacc[4][4];  // attnT[m=mt*16+4lq+j][n=nt*16+lr]
#pragma unroll
  for (int mt = 0; mt < 4; ++mt)
#pragma unroll
    for (int nt = 0; nt < 4; ++nt) {
      f32x4 z = {0.f, 0.f, 0.f, 0.f};
      sacc[mt][nt] = __builtin_amdgcn_mfma_f32_16x16x32_bf16(afr[mt], bfr[nt], z, 0, 0, 0);
    }
  float rden[4];
  {
    const float* bias_h = biasf + wv * 4096;
    const float* mask_w = mask_g + (size_t)wd * 4096;
#pragma unroll
    for (int nt = 0; nt < 4; ++nt) {
      int n = nt * 16 + lr;
      float lmx = -1e30f;
#pragma unroll
      for (int mt = 0; mt < 4; ++mt) {
        int m0 = mt * 16 + 4 * lq;
        float4 bi = *(const float4*)(bias_h + n * 64 + m0);
        float4 mk = *(const float4*)(mask_w + n * 64 + m0);
        sacc[mt][nt][0] += bi.x + mk.x;
        sacc[mt][nt][1] += bi.y + mk.y;
        sacc[mt][nt][2] += bi.z + mk.z;
        sacc[mt][nt][3] += bi.w + mk.w;
        lmx = fmaxf(lmx, fmaxf(fmaxf(sacc[mt][nt][0], sacc[mt][nt][1]),
                               fmaxf(sacc[mt][nt][2], sacc[mt][nt][3])));
      }
      lmx = fmaxf(lmx, __shfl_xor(lmx, 16));
      lmx = fmaxf(lmx, __shfl_xor(lmx, 32));
      float ls = 0.f;
#pragma unroll
      for (int mt = 0; mt < 4; ++mt) {
#pragma unroll
        for (int j = 0; j < 4; ++j) {
          float e = __expf(sacc[mt][nt][j] - lmx);
          sacc[mt][nt][j] = e;
          ls += e;
        }
      }
      ls += __shfl_xor(ls, 16);
      ls += __shfl_xor(ls, 32);
      rden[nt] = 1.0f / ls;
    }
  }

  // ---- P in-wave transpose -> B-fragments pfr[kk][nt]: P[n=nt*16+lr][m=kk*32+8lq..+7]
  bf16x8 pfr[2][4];
#pragma unroll
  for (int kk = 0; kk < 2; ++kk) {
#pragma unroll
    for (int nt = 0; nt < 4; ++nt) {
      u32 s0 = pack2(sacc[2 * kk][nt][0], sacc[2 * kk][nt][1]);
      u32 s1 = pack2(sacc[2 * kk][nt][2], sacc[2 * kk][nt][3]);
      u32 s2 = pack2(sacc[2 * kk + 1][nt][0], sacc[2 * kk + 1][nt][1]);
      u32 s3 = pack2(sacc[2 * kk + 1][nt][2], sacc[2 * kk + 1][nt][3]);
      u32 a00 = (u32)__shfl((int)s0, srcA), a20 = (u32)__shfl((int)s2, srcA);
      u32 a01 = (u32)__shfl((int)s1, srcA), a21 = (u32)__shfl((int)s3, srcA);
      u32 b00 = (u32)__shfl((int)s0, srcB), b20 = (u32)__shfl((int)s2, srcB);
      u32 b01 = (u32)__shfl((int)s1, srcB), b21 = (u32)__shfl((int)s3, srcB);
      uint4 u;
      u.x = hi ? a20 : a00;
      u.y = hi ? a21 : a01;
      u.z = hi ? b20 : b00;
      u.w = hi ? b21 : b01;
      pfr[kk][nt] = __builtin_bit_cast(bf16x8, u);
    }
  }

  // ---- PV: outT[ch][n] = sum_m VT[ch][m] * P[n][m]
  f32x4 oacc[2][4];
#pragma unroll
  for (int i = 0; i < 2; ++i)
#pragma unroll
    for (int j = 0; j < 4; ++j) oacc[i][j] = {0.f, 0.f, 0.f, 0.f};
#pragma unroll
  for (int kk = 0; kk < 2; ++kk) {
    int mB = (kk * 32 + 8 * lq) * 2;
    int ch0 = wv * 32 + lr;
    int ch1 = ch0 + 16;
    bf16x8 va0 = *(const bf16x8*)(smem + R0_OFF + ch0 * 128 + (mB ^ ((ch0 & 7) << 4)));
    bf16x8 va1 = *(const bf16x8*)(smem + R0_OFF + ch1 * 128 + (mB ^ ((ch1 & 7) << 4)));
#pragma unroll
    for (int nt = 0; nt < 4; ++nt) {
      oacc[0][nt] = __builtin_amdgcn_mfma_f32_16x16x32_bf16(va0, pfr[kk][nt], oacc[0][nt], 0, 0, 0);
      oacc[1][nt] = __builtin_amdgcn_mfma_f32_16x16x32_bf16(va1, pfr[kk][nt], oacc[1][nt], 0, 0, 0);
    }
  }
  // normalize + write O tile [t][c] into R1 (own columns)
#pragma unroll
  for (int dt = 0; dt < 2; ++dt) {
    int cb = wv * 32 + dt * 16 + 4 * lq;
#pragma unroll
    for (int nt = 0; nt < 4; ++nt) {
      int n = nt * 16 + lr;
      float r = rden[nt];
      uint2 w;
      w.x = pack2(oacc[dt][nt][0] * r, oacc[dt][nt][1] * r);
      w.y = pack2(oacc[dt][nt][2] * r, oacc[dt][nt][3] * r);
      *(uint2*)(smem + R1_OFF + n * XROW + cb * 2) = w;
    }
  }
  __syncthreads();  // B5: O complete

  // ---- output projection
  {
    f32x4 acc[4][2];
#pragma unroll
    for (int i = 0; i < 4; ++i)
#pragma unroll
      for (int j = 0; j < 2; ++j) acc[i][j] = {0.f, 0.f, 0.f, 0.f};
    const int kl = 8 * lq;
    const int prow0 = wv * 32 + lr;
#pragma unroll
    for (int kk = 0; kk < 8; ++kk) {
      int c = kk * 32 + kl;
      bf16x8 b0 = *(const bf16x8*)(pjw + (prow0) * 256 + c);
      bf16x8 b1 = *(const bf16x8*)(pjw + (prow0 + 16) * 256 + c);
#pragma unroll
      for (int mt = 0; mt < 4; ++mt) {
        bf16x8 at = *(const bf16x8*)(smem + R1_OFF + (mt * 16 + lr) * XROW + c * 2);
        acc[mt][0] = __builtin_amdgcn_mfma_f32_16x16x32_bf16(at, b0, acc[mt][0], 0, 0, 0);
        acc[mt][1] = __builtin_amdgcn_mfma_f32_16x16x32_bf16(at, b1, acc[mt][1], 0, 0, 0);
      }
    }
    float* outb = out_g + (size_t)b * 16384;
#pragma unroll
    for (int ntl = 0; ntl < 2; ++ntl) {
      int c = wv * 32 + ntl * 16 + lr;
      float pbv = pb_g[c];
#pragma unroll
      for (int mt = 0; mt < 4; ++mt) {
        int t = mt * 16 + 4 * lq;
        outb[(t + 0) * 256 + c] = acc[mt][ntl][0] + pbv;
        outb[(t + 1) * 256 + c] = acc[mt][ntl][1] + pbv;
        outb[(t + 2) * 256 + c] = acc[mt][ntl][2] + pbv;
        outb[(t + 3) * 256 + c] = acc[mt][ntl][3] + pbv;
      }
    }
  }
}

extern "C" void kernel_launch(void* const* d_in, const int* in_sizes, int n_in,
                              void* d_out, int out_size, void* d_ws, size_t ws_size,
                              hipStream_t stream) {
  const float* ref = (const float*)d_in[0];
  const float* adj = (const float*)d_in[1];
  const float* mask = (const float*)d_in[2];
  const float* q_w = (const float*)d_in[3];
  const float* q_b = (const float*)d_in[4];
  const float* kv_w = (const float*)d_in[5];
  const float* kv_b = (const float*)d_in[6];
  const float* proj_w = (const float*)d_in[7];
  const float* proj_b = (const float*)d_in[8];
  const float* rpb = (const float*)d_in[9];

  u16* qw = (u16*)d_ws;
  u16* kvw = qw + 65536;
  u16* pjw = kvw + 131072;
  float* biasf = (float*)(pjw + 65536);

  prep_kern<<<1152, 256, 0, stream>>>(q_w, kv_w, proj_w, rpb, qw, kvw, pjw, biasf);

  int B = in_sizes[0] / 16384;           // 4096
  int nW = in_sizes[2] / 4096;           // 1024
  hipFuncSetAttribute((const void*)winattn_kern, hipFuncAttributeMaxDynamicSharedMemorySize,
                      LDS_TOTAL);
  winattn_kern<<<B, 512, LDS_TOTAL, stream>>>(ref, adj, mask, q_b, kv_b, proj_b, qw, kvw, pjw,
                                              biasf, (float*)d_out, nW);
}

// Round 3
// 577.843 us; speedup vs baseline: 1.1136x; 1.1136x over previous
//
#include <hip/hip_runtime.h>

typedef unsigned short u16;
typedef unsigned int u32;
typedef float f32x4 __attribute__((ext_vector_type(4)));
typedef __bf16 bf16x8 __attribute__((ext_vector_type(8)));

__device__ __forceinline__ u16 f2bf(float f) {
  unsigned u = __builtin_bit_cast(unsigned, f);
  u += 0x7FFFu + ((u >> 16) & 1u);
  return (u16)(u >> 16);
}
__device__ __forceinline__ u32 pack2(float a, float b) {
  return (u32)f2bf(a) | ((u32)f2bf(b) << 16);
}

// ---- prep: convert weights f32->bf16 into ws, expand rel-pos bias to [8][64][64] f32
__global__ void prep_kern(const float* __restrict__ qw_f, const float* __restrict__ kvw_f,
                          const float* __restrict__ pjw_f, const float* __restrict__ rpb,
                          u16* __restrict__ qw, u16* __restrict__ kvw, u16* __restrict__ pjw,
                          float* __restrict__ biasf) {
  int i = blockIdx.x * 256 + threadIdx.x;
  if (i < 65536) {
    qw[i] = f2bf(qw_f[i]);
  } else if (i < 196608) {
    kvw[i - 65536] = f2bf(kvw_f[i - 65536]);
  } else if (i < 262144) {
    pjw[i - 196608] = f2bf(pjw_f[i - 196608]);
  } else if (i < 294912) {
    int t = i - 262144;                 // [h][n][m]
    int h = t >> 12, n = (t >> 6) & 63, m = t & 63;
    int r1 = n >> 3, c1 = n & 7, r2 = m >> 3, c2 = m & 7;
    int rp = (r1 - r2 + 7) * 15 + (c1 - c2 + 7);
    biasf[t] = rpb[rp * 8 + h];
  }
}

// LDS: two 33792B regions. R0: stage (ref->adj) then VT-swizzled [256][64].
//      R1: Q tile [64][264] then O tile [64][264].
#define XROW 528
#define R0_OFF 0
#define R1_OFF 33792
#define LDS_TOTAL 67584

__global__ __launch_bounds__(512, 2) void winattn_kern(
    const float* __restrict__ xr_g, const float* __restrict__ xa_g,
    const float* __restrict__ mask_g,
    const float* __restrict__ qb_g, const float* __restrict__ kvb_g, const float* __restrict__ pb_g,
    const u16* __restrict__ qw, const u16* __restrict__ kvw, const u16* __restrict__ pjw,
    const float* __restrict__ biasf, float* __restrict__ out_g, int nW) {
  extern __shared__ char smem[];
  const int tid = threadIdx.x;
  const int l = tid & 63, wv = tid >> 6;
  const int lr = l & 15, lq = l >> 4;
  const int b = blockIdx.x;
  const int wd = b % nW;
  const float scale = 0.17677669529663687f;  // 1/sqrt(32)

  // ---- stage a [64][256] f32 tile into R0 as bf16 [64][264]
  auto stage = [&](const float* src) {
#pragma unroll
    for (int it = 0; it < 8; ++it) {
      int flat = it * 512 + tid;
      int t = flat >> 6, c4 = (flat & 63) << 2;
      float4 v = *(const float4*)(src + t * 256 + c4);
      uint2 w;
      w.x = pack2(v.x, v.y);
      w.y = pack2(v.z, v.w);
      *(uint2*)(smem + R0_OFF + t * XROW + c4 * 2) = w;
    }
  };

  const float* refb = xr_g + (size_t)b * 16384;
  const float* adjb = xa_g + (size_t)b * 16384;

  stage(refb);
  __syncthreads();  // B1: ref staged

  // ---- Q-gemm (transposed): D[c][t] = sum_k qw[c][k]*x[t][k]; store [t][c] into R1
  {
    f32x4 acc[2][4];
#pragma unroll
    for (int i = 0; i < 2; ++i)
#pragma unroll
      for (int j = 0; j < 4; ++j) acc[i][j] = {0.f, 0.f, 0.f, 0.f};
    const int row0 = wv * 32 + lr;
    const int kl = 8 * lq;
#pragma unroll
    for (int kk = 0; kk < 8; ++kk) {
      int c = kk * 32 + kl;
      bf16x8 a0 = *(const bf16x8*)(qw + (row0) * 256 + c);
      bf16x8 a1 = *(const bf16x8*)(qw + (row0 + 16) * 256 + c);
#pragma unroll
      for (int nt = 0; nt < 4; ++nt) {
        bf16x8 bt = *(const bf16x8*)(smem + R0_OFF + (nt * 16 + lr) * XROW + c * 2);
        acc[0][nt] = __builtin_amdgcn_mfma_f32_16x16x32_bf16(a0, bt, acc[0][nt], 0, 0, 0);
        acc[1][nt] = __builtin_amdgcn_mfma_f32_16x16x32_bf16(a1, bt, acc[1][nt], 0, 0, 0);
      }
    }
#pragma unroll
    for (int mt = 0; mt < 2; ++mt) {
      int cb = wv * 32 + mt * 16 + 4 * lq;
      float4 b4 = *(const float4*)(qb_g + cb);
#pragma unroll
      for (int nt = 0; nt < 4; ++nt) {
        int t = lr + nt * 16;
        uint2 w;
        w.x = pack2((acc[mt][nt][0] + b4.x) * scale, (acc[mt][nt][1] + b4.y) * scale);
        w.y = pack2((acc[mt][nt][2] + b4.z) * scale, (acc[mt][nt][3] + b4.w) * scale);
        *(uint2*)(smem + R1_OFF + t * XROW + cb * 2) = w;
      }
    }
  }
  __syncthreads();  // B2: Q-gemm reads of R0 done

  stage(adjb);
  __syncthreads();  // B3: adj staged

  const int srcA = lr + 32 * (lq & 1);
  const int srcB = srcA + 16;
  const bool hi = (lq >> 1) != 0;

  // ---- K-gemm (transposed, acc in regs) then in-wave transpose -> A-fragments
  bf16x8 afr[4];
  {
    f32x4 kacc[2][4];
#pragma unroll
    for (int i = 0; i < 2; ++i)
#pragma unroll
      for (int j = 0; j < 4; ++j) kacc[i][j] = {0.f, 0.f, 0.f, 0.f};
    const int row0 = wv * 32 + lr;
    const int kl = 8 * lq;
#pragma unroll
    for (int kk = 0; kk < 8; ++kk) {
      int c = kk * 32 + kl;
      bf16x8 a0 = *(const bf16x8*)(kvw + (row0) * 256 + c);
      bf16x8 a1 = *(const bf16x8*)(kvw + (row0 + 16) * 256 + c);
#pragma unroll
      for (int nt = 0; nt < 4; ++nt) {
        bf16x8 bt = *(const bf16x8*)(smem + R0_OFF + (nt * 16 + lr) * XROW + c * 2);
        kacc[0][nt] = __builtin_amdgcn_mfma_f32_16x16x32_bf16(a0, bt, kacc[0][nt], 0, 0, 0);
        kacc[1][nt] = __builtin_amdgcn_mfma_f32_16x16x32_bf16(a1, bt, kacc[1][nt], 0, 0, 0);
      }
    }
    // bias: channel = wv*32 + mt*16 + 4lq + j
    float4 kb0 = *(const float4*)(kvb_g + wv * 32 + 4 * lq);
    float4 kb1 = *(const float4*)(kvb_g + wv * 32 + 16 + 4 * lq);
#pragma unroll
    for (int nt = 0; nt < 4; ++nt) {
      kacc[0][nt][0] += kb0.x; kacc[0][nt][1] += kb0.y; kacc[0][nt][2] += kb0.z; kacc[0][nt][3] += kb0.w;
      kacc[1][nt][0] += kb1.x; kacc[1][nt][1] += kb1.y; kacc[1][nt][2] += kb1.z; kacc[1][nt][3] += kb1.w;
    }
    // transpose: afr[nt] lane(lr,lq) = K[t=nt*16+lr][ch=8lq..8lq+7]
#pragma unroll
    for (int nt = 0; nt < 4; ++nt) {
      u32 s0 = pack2(kacc[0][nt][0], kacc[0][nt][1]);
      u32 s1 = pack2(kacc[0][nt][2], kacc[0][nt][3]);
      u32 s2 = pack2(kacc[1][nt][0], kacc[1][nt][1]);
      u32 s3 = pack2(kacc[1][nt][2], kacc[1][nt][3]);
      u32 a00 = (u32)__shfl((int)s0, srcA), a20 = (u32)__shfl((int)s2, srcA);
      u32 a01 = (u32)__shfl((int)s1, srcA), a21 = (u32)__shfl((int)s3, srcA);
      u32 b00 = (u32)__shfl((int)s0, srcB), b20 = (u32)__shfl((int)s2, srcB);
      u32 b01 = (u32)__shfl((int)s1, srcB), b21 = (u32)__shfl((int)s3, srcB);
      uint4 u;
      u.x = hi ? a20 : a00;
      u.y = hi ? a21 : a01;
      u.z = hi ? b20 : b00;
      u.w = hi ? b21 : b01;
      afr[nt] = __builtin_bit_cast(bf16x8, u);
    }
  }

  // ---- Q fragments from R1 (own wave's columns)
  bf16x8 bfr[4];
  {
    const int c0 = wv * 32 + 8 * lq;
#pragma unroll
    for (int nt = 0; nt < 4; ++nt)
      bfr[nt] = *(const bf16x8*)(smem + R1_OFF + (nt * 16 + lr) * XROW + c0 * 2);
  }

  // ---- QK^T + softmax (head h = wv)
  f32x4 sacc[4][4];  // attnT[m=mt*16+4lq+j][n=nt*16+lr]
#pragma unroll
  for (int mt = 0; mt < 4; ++mt)
#pragma unroll
    for (int nt = 0; nt < 4; ++nt) {
      f32x4 z = {0.f, 0.f, 0.f, 0.f};
      sacc[mt][nt] = __builtin_amdgcn_mfma_f32_16x16x32_bf16(afr[mt], bfr[nt], z, 0, 0, 0);
    }
  float rden[4];
  {
    const float* bias_h = biasf + wv * 4096;
    const float* mask_w = mask_g + (size_t)wd * 4096;
#pragma unroll
    for (int nt = 0; nt < 4; ++nt) {
      int n = nt * 16 + lr;
      float lmx = -1e30f;
#pragma unroll
      for (int mt = 0; mt < 4; ++mt) {
        int m0 = mt * 16 + 4 * lq;
        float4 bi = *(const float4*)(bias_h + n * 64 + m0);
        float4 mk = *(const float4*)(mask_w + n * 64 + m0);
        sacc[mt][nt][0] += bi.x + mk.x;
        sacc[mt][nt][1] += bi.y + mk.y;
        sacc[mt][nt][2] += bi.z + mk.z;
        sacc[mt][nt][3] += bi.w + mk.w;
        lmx = fmaxf(lmx, fmaxf(fmaxf(sacc[mt][nt][0], sacc[mt][nt][1]),
                               fmaxf(sacc[mt][nt][2], sacc[mt][nt][3])));
      }
      lmx = fmaxf(lmx, __shfl_xor(lmx, 16));
      lmx = fmaxf(lmx, __shfl_xor(lmx, 32));
      float ls = 0.f;
#pragma unroll
      for (int mt = 0; mt < 4; ++mt) {
#pragma unroll
        for (int j = 0; j < 4; ++j) {
          float e = __expf(sacc[mt][nt][j] - lmx);
          sacc[mt][nt][j] = e;
          ls += e;
        }
      }
      ls += __shfl_xor(ls, 16);
      ls += __shfl_xor(ls, 32);
      rden[nt] = 1.0f / ls;
    }
  }

  // ---- P in-wave transpose -> B-fragments pfr[kk][nt]: P[n=nt*16+lr][m=kk*32+8lq..+7]
  bf16x8 pfr[2][4];
#pragma unroll
  for (int kk = 0; kk < 2; ++kk) {
#pragma unroll
    for (int nt = 0; nt < 4; ++nt) {
      u32 s0 = pack2(sacc[2 * kk][nt][0], sacc[2 * kk][nt][1]);
      u32 s1 = pack2(sacc[2 * kk][nt][2], sacc[2 * kk][nt][3]);
      u32 s2 = pack2(sacc[2 * kk + 1][nt][0], sacc[2 * kk + 1][nt][1]);
      u32 s3 = pack2(sacc[2 * kk + 1][nt][2], sacc[2 * kk + 1][nt][3]);
      u32 a00 = (u32)__shfl((int)s0, srcA), a20 = (u32)__shfl((int)s2, srcA);
      u32 a01 = (u32)__shfl((int)s1, srcA), a21 = (u32)__shfl((int)s3, srcA);
      u32 b00 = (u32)__shfl((int)s0, srcB), b20 = (u32)__shfl((int)s2, srcB);
      u32 b01 = (u32)__shfl((int)s1, srcB), b21 = (u32)__shfl((int)s3, srcB);
      uint4 u;
      u.x = hi ? a20 : a00;
      u.y = hi ? a21 : a01;
      u.z = hi ? b20 : b00;
      u.w = hi ? b21 : b01;
      pfr[kk][nt] = __builtin_bit_cast(bf16x8, u);
    }
  }

  // ---- V-gemm (non-transposed, acc in regs) -- after P to cut peak reg pressure
  f32x4 vacc[4][2];
  {
#pragma unroll
    for (int i = 0; i < 4; ++i)
#pragma unroll
      for (int j = 0; j < 2; ++j) vacc[i][j] = {0.f, 0.f, 0.f, 0.f};
    const int kl = 8 * lq;
    const int vrow0 = 256 + wv * 32 + lr;
#pragma unroll
    for (int kk = 0; kk < 8; ++kk) {
      int c = kk * 32 + kl;
      bf16x8 b0 = *(const bf16x8*)(kvw + (vrow0) * 256 + c);
      bf16x8 b1 = *(const bf16x8*)(kvw + (vrow0 + 16) * 256 + c);
#pragma unroll
      for (int mt = 0; mt < 4; ++mt) {
        bf16x8 at = *(const bf16x8*)(smem + R0_OFF + (mt * 16 + lr) * XROW + c * 2);
        vacc[mt][0] = __builtin_amdgcn_mfma_f32_16x16x32_bf16(at, b0, vacc[mt][0], 0, 0, 0);
        vacc[mt][1] = __builtin_amdgcn_mfma_f32_16x16x32_bf16(at, b1, vacc[mt][1], 0, 0, 0);
      }
    }
    float bv0 = kvb_g[256 + wv * 32 + lr];
    float bv1 = kvb_g[256 + wv * 32 + 16 + lr];
#pragma unroll
    for (int mt = 0; mt < 4; ++mt)
#pragma unroll
      for (int j = 0; j < 4; ++j) {
        vacc[mt][0][j] += bv0;
        vacc[mt][1][j] += bv1;
      }
  }
  __syncthreads();  // B4: all R0 reads done; VT may overwrite R0

  // ---- write VT (swizzled [256 ch][64 tok] bf16) into R0
  {
#pragma unroll
    for (int ntl = 0; ntl < 2; ++ntl) {
      int ch = wv * 32 + ntl * 16 + lr;
      int swz = (ch & 7) << 4;
      char* base = smem + R0_OFF + ch * 128;
#pragma unroll
      for (int mt = 0; mt < 4; ++mt) {
        int tB = (mt * 16 + 4 * lq) * 2;
        uint2 w;
        w.x = pack2(vacc[mt][ntl][0], vacc[mt][ntl][1]);
        w.y = pack2(vacc[mt][ntl][2], vacc[mt][ntl][3]);
        *(uint2*)(base + (tB ^ swz)) = w;
      }
    }
  }

  // ---- PV: outT[ch][n] = sum_m VT[ch][m] * P[n][m]  (VT rows are own-wave-written)
  f32x4 oacc[2][4];
#pragma unroll
  for (int i = 0; i < 2; ++i)
#pragma unroll
    for (int j = 0; j < 4; ++j) oacc[i][j] = {0.f, 0.f, 0.f, 0.f};
#pragma unroll
  for (int kk = 0; kk < 2; ++kk) {
    int mB = (kk * 32 + 8 * lq) * 2;
    int ch0 = wv * 32 + lr;
    int ch1 = ch0 + 16;
    bf16x8 va0 = *(const bf16x8*)(smem + R0_OFF + ch0 * 128 + (mB ^ ((ch0 & 7) << 4)));
    bf16x8 va1 = *(const bf16x8*)(smem + R0_OFF + ch1 * 128 + (mB ^ ((ch1 & 7) << 4)));
#pragma unroll
    for (int nt = 0; nt < 4; ++nt) {
      oacc[0][nt] = __builtin_amdgcn_mfma_f32_16x16x32_bf16(va0, pfr[kk][nt], oacc[0][nt], 0, 0, 0);
      oacc[1][nt] = __builtin_amdgcn_mfma_f32_16x16x32_bf16(va1, pfr[kk][nt], oacc[1][nt], 0, 0, 0);
    }
  }
  // normalize + write O tile [t][c] into R1 (own columns)
#pragma unroll
  for (int dt = 0; dt < 2; ++dt) {
    int cb = wv * 32 + dt * 16 + 4 * lq;
#pragma unroll
    for (int nt = 0; nt < 4; ++nt) {
      int n = nt * 16 + lr;
      float r = rden[nt];
      uint2 w;
      w.x = pack2(oacc[dt][nt][0] * r, oacc[dt][nt][1] * r);
      w.y = pack2(oacc[dt][nt][2] * r, oacc[dt][nt][3] * r);
      *(uint2*)(smem + R1_OFF + n * XROW + cb * 2) = w;
    }
  }
  __syncthreads();  // B5: O complete

  // ---- output projection
  {
    f32x4 acc[4][2];
#pragma unroll
    for (int i = 0; i < 4; ++i)
#pragma unroll
      for (int j = 0; j < 2; ++j) acc[i][j] = {0.f, 0.f, 0.f, 0.f};
    const int kl = 8 * lq;
    const int prow0 = wv * 32 + lr;
#pragma unroll
    for (int kk = 0; kk < 8; ++kk) {
      int c = kk * 32 + kl;
      bf16x8 b0 = *(const bf16x8*)(pjw + (prow0) * 256 + c);
      bf16x8 b1 = *(const bf16x8*)(pjw + (prow0 + 16) * 256 + c);
#pragma unroll
      for (int mt = 0; mt < 4; ++mt) {
        bf16x8 at = *(const bf16x8*)(smem + R1_OFF + (mt * 16 + lr) * XROW + c * 2);
        acc[mt][0] = __builtin_amdgcn_mfma_f32_16x16x32_bf16(at, b0, acc[mt][0], 0, 0, 0);
        acc[mt][1] = __builtin_amdgcn_mfma_f32_16x16x32_bf16(at, b1, acc[mt][1], 0, 0, 0);
      }
    }
    float* outb = out_g + (size_t)b * 16384;
#pragma unroll
    for (int ntl = 0; ntl < 2; ++ntl) {
      int c = wv * 32 + ntl * 16 + lr;
      float pbv = pb_g[c];
#pragma unroll
      for (int mt = 0; mt < 4; ++mt) {
        int t = mt * 16 + 4 * lq;
        outb[(t + 0) * 256 + c] = acc[mt][ntl][0] + pbv;
        outb[(t + 1) * 256 + c] = acc[mt][ntl][1] + pbv;
        outb[(t + 2) * 256 + c] = acc[mt][ntl][2] + pbv;
        outb[(t + 3) * 256 + c] = acc[mt][ntl][3] + pbv;
      }
    }
  }
}

extern "C" void kernel_launch(void* const* d_in, const int* in_sizes, int n_in,
                              void* d_out, int out_size, void* d_ws, size_t ws_size,
                              hipStream_t stream) {
  const float* ref = (const float*)d_in[0];
  const float* adj = (const float*)d_in[1];
  const float* mask = (const float*)d_in[2];
  const float* q_w = (const float*)d_in[3];
  const float* q_b = (const float*)d_in[4];
  const float* kv_w = (const float*)d_in[5];
  const float* kv_b = (const float*)d_in[6];
  const float* proj_w = (const float*)d_in[7];
  const float* proj_b = (const float*)d_in[8];
  const float* rpb = (const float*)d_in[9];

  u16* qw = (u16*)d_ws;
  u16* kvw = qw + 65536;
  u16* pjw = kvw + 131072;
  float* biasf = (float*)(pjw + 65536);

  prep_kern<<<1152, 256, 0, stream>>>(q_w, kv_w, proj_w, rpb, qw, kvw, pjw, biasf);

  int B = in_sizes[0] / 16384;           // 4096
  int nW = in_sizes[2] / 4096;           // 1024
  hipFuncSetAttribute((const void*)winattn_kern, hipFuncAttributeMaxDynamicSharedMemorySize,
                      LDS_TOTAL);
  winattn_kern<<<B, 512, LDS_TOTAL, stream>>>(ref, adj, mask, q_b, kv_b, proj_b, qw, kvw, pjw,
                                              biasf, (float*)d_out, nW);
}